// Round 7
// baseline (3848.811 us; speedup 1.0000x reference)
//
#include <hip/hip_runtime.h>
#include <math.h>

#define SEQ 512
#define HID 512
#define NGROUP 8              // batch groups of 16; group g = bid & 7
#define GB 16                 // batches per group
#define BPG 32                // blocks per group (each owns 16 n-cols)
#define LROW 520              // LDS row stride in ushorts
#define UNITS_PER_GROUP 3072  // 512 chunks * 6 units (chunk = one producer x one batch)
#define UNITS_PER_SLOT 24576  // 8 groups * 3072
// Unit = 8 B = {bf16 h0, bf16 h1, bf16 h2, u16 tag}. tag == consuming step t.
// Chunk ci = cb*16 + b holds producer cb's 16 cols for batch b as 6 units
// (units 0..4: cols 3u..3u+2; unit 5: col 15 only, upper data slots ignored).
// ws layout: two unit slots (2 * 192 KB). No flags -- tags ARE the handshake.

typedef __attribute__((ext_vector_type(8))) short short8;   // 8 bf16 (MFMA A/B frag)
typedef __attribute__((ext_vector_type(4))) float floatx4;  // MFMA C/D

__device__ __forceinline__ unsigned short f2bf(float f) {   // RNE fp32->bf16
    unsigned u = __builtin_bit_cast(unsigned, f);
    return (unsigned short)((u + 0x7FFFu + ((u >> 16) & 1u)) >> 16);
}
__device__ __forceinline__ float bf2f(unsigned short h) {
    unsigned u = ((unsigned)h) << 16;
    return __builtin_bit_cast(float, u);
}
__device__ __forceinline__ float fast_sigmoid(float x) {
    return 1.0f / (1.0f + __expf(-x));
}
__device__ __forceinline__ float fast_tanh(float x) {
    float e = __expf(-2.0f * fabsf(x));
    float t = (1.0f - e) / (1.0f + e);
    return x < 0.0f ? -t : t;
}

__global__ void lstm_init(const float* __restrict__ H0, unsigned long long* __restrict__ ub) {
    int idx = blockIdx.x * blockDim.x + threadIdx.x;   // one unit per thread
    if (idx >= UNITS_PER_SLOT) return;
    int g   = idx / UNITS_PER_GROUP;
    int rem = idx - g * UNITS_PER_GROUP;
    int ci  = rem / 6;
    int u   = rem - ci * 6;
    int cb  = ci >> 4, b = ci & 15;
    int row = (g * GB + b) * HID;
    int c0  = cb * 16 + 3 * u;
    int c1  = min(c0 + 1, 511), c2 = min(c0 + 2, 511);  // u==5 upper slots: ignored by consumers
    unsigned long long v = (unsigned long long)f2bf(H0[row + c0])
                         | ((unsigned long long)f2bf(H0[row + c1]) << 16)
                         | ((unsigned long long)f2bf(H0[row + c2]) << 32);
    ub[idx] = v;                                        // tag = 0 (step 0 input)
}

__global__ __launch_bounds__(256, 1)
void lstm_main(const float* __restrict__ x,
               const float* __restrict__ C0,
               const float* __restrict__ Wi, const float* __restrict__ bi,
               const float* __restrict__ Wf, const float* __restrict__ bf_,
               const float* __restrict__ Wc, const float* __restrict__ bc,
               const float* __restrict__ Wo, const float* __restrict__ bo,
               float* __restrict__ out, unsigned long long* __restrict__ ub) {
    const int bid  = blockIdx.x;
    const int g    = bid & 7;
    const int cb   = bid >> 3;
    const int tid  = threadIdx.x;
    const int w    = tid >> 6;          // wave 0..3
    const int lane = tid & 63;
    const int q    = lane >> 4;         // quad
    const int c    = lane & 15;

    // MFMA roles (verified layouts): A[m=lane&15][k=q*8+j], B[k=q*8+j][n=lane&15],
    // D[m=q*4+r][n=lane&15] with m = col_local*4 + gate.
    const int gate = c & 3;
    const int colA = cb * 16 + w * 4 + (c >> 2);
    const int colD = cb * 16 + w * 4 + q;     // this lane's output column
    const int bD   = g * GB + c;              // this lane's batch

    // ---- step-invariant A-fragments: hi+lo bf16 split of W, in registers ----
    const float* Wg = (gate == 0) ? Wi : (gate == 1) ? Wf : (gate == 2) ? Wc : Wo;
    short8 aHi[16], aLo[16];
    #pragma unroll
    for (int kt = 0; kt < 16; ++kt) {
        #pragma unroll
        for (int j = 0; j < 8; ++j) {
            int k = kt * 32 + q * 8 + j;
            float wv = Wg[(k + 1) * HID + colA];   // rows 1..512 = H weights
            unsigned short hi = f2bf(wv);
            unsigned short lo = f2bf(wv - bf2f(hi));
            aHi[kt][j] = (short)hi;
            aLo[kt][j] = (short)lo;
        }
    }

    const float biasI = bi[colD], biasF = bf_[colD], biasC = bc[colD], biasO = bo[colD];
    const float w0I = Wi[colD], w0F = Wf[colD], w0C = Wc[colD], w0O = Wo[colD];
    float Cst = C0[bD * HID + colD];
    const float* xrow = x + bD * SEQ;

    __shared__ unsigned short hlds[16 * LROW];   // staged H tile [b][k] bf16
    __shared__ unsigned short hout[16 * 16 + 2]; // this block's step output (flat [b*16+col])

    // precomputed consumer mapping: lane -> chunks 2*tid, 2*tid+1 (96 contiguous bytes)
    const int ciA = 2 * tid,      ciB = 2 * tid + 1;
    const int ldsA = (ciA & 15) * LROW + (ciA >> 4) * 16;   // ushort offset, 16B-aligned
    const int ldsB = (ciB & 15) * LROW + (ciB >> 4) * 16;
    // precomputed producer mapping: lane tid<96 -> unit tid of this block's 96
    const int punit = cb * 96 + tid;                        // unit offset within group slot
    const int pb16  = (tid / 6) * 16 + 3 * (tid - (tid / 6) * 6);  // hout flat index

    for (int t = 0; t < SEQ; ++t) {
        // ---- poll-load: 12 coalesced dwordx2; tags==t validate the data itself ----
        const unsigned long long* up = ub + (t & 1) * UNITS_PER_SLOT
                                          + g * UNITS_PER_GROUP + tid * 12;
        const unsigned long long tg = (unsigned long long)t;
        unsigned long long v0, v1, v2, v3, v4, v5, v6, v7, v8, v9, v10, v11;
        while (1) {
            asm volatile(
                "global_load_dwordx2 %0, %12, off sc0 sc1\n\t"
                "global_load_dwordx2 %1, %12, off offset:8 sc0 sc1\n\t"
                "global_load_dwordx2 %2, %12, off offset:16 sc0 sc1\n\t"
                "global_load_dwordx2 %3, %12, off offset:24 sc0 sc1\n\t"
                "global_load_dwordx2 %4, %12, off offset:32 sc0 sc1\n\t"
                "global_load_dwordx2 %5, %12, off offset:40 sc0 sc1\n\t"
                "global_load_dwordx2 %6, %12, off offset:48 sc0 sc1\n\t"
                "global_load_dwordx2 %7, %12, off offset:56 sc0 sc1\n\t"
                "global_load_dwordx2 %8, %12, off offset:64 sc0 sc1\n\t"
                "global_load_dwordx2 %9, %12, off offset:72 sc0 sc1\n\t"
                "global_load_dwordx2 %10, %12, off offset:80 sc0 sc1\n\t"
                "global_load_dwordx2 %11, %12, off offset:88 sc0 sc1\n\t"
                "s_waitcnt vmcnt(0)"
                : "=&v"(v0), "=&v"(v1), "=&v"(v2), "=&v"(v3), "=&v"(v4), "=&v"(v5),
                  "=&v"(v6), "=&v"(v7), "=&v"(v8), "=&v"(v9), "=&v"(v10), "=&v"(v11)
                : "v"(up) : "memory");
            unsigned long long bad =
                ((v0 >> 48) ^ tg) | ((v1 >> 48) ^ tg) | ((v2 >> 48) ^ tg) |
                ((v3 >> 48) ^ tg) | ((v4 >> 48) ^ tg) | ((v5 >> 48) ^ tg) |
                ((v6 >> 48) ^ tg) | ((v7 >> 48) ^ tg) | ((v8 >> 48) ^ tg) |
                ((v9 >> 48) ^ tg) | ((v10 >> 48) ^ tg) | ((v11 >> 48) ^ tg);
            if (bad == 0) break;
            __builtin_amdgcn_s_sleep(1);
        }

        // ---- unpack 2 chunks (16 bf16 each) -> LDS rows ----
        {
            unsigned d0 = (unsigned)v0;
            unsigned d1 = (unsigned)((v0 >> 32) & 0xFFFF) | ((unsigned)(v1 & 0xFFFF) << 16);
            unsigned d2 = (unsigned)(v1 >> 16);
            unsigned d3 = (unsigned)v2;
            unsigned d4 = (unsigned)((v2 >> 32) & 0xFFFF) | ((unsigned)(v3 & 0xFFFF) << 16);
            unsigned d5 = (unsigned)(v3 >> 16);
            unsigned d6 = (unsigned)v4;
            unsigned d7 = (unsigned)((v4 >> 32) & 0xFFFF) | ((unsigned)(v5 & 0xFFFF) << 16);
            *(uint4*)&hlds[ldsA]     = make_uint4(d0, d1, d2, d3);
            *(uint4*)&hlds[ldsA + 8] = make_uint4(d4, d5, d6, d7);
            unsigned e0 = (unsigned)v6;
            unsigned e1 = (unsigned)((v6 >> 32) & 0xFFFF) | ((unsigned)(v7 & 0xFFFF) << 16);
            unsigned e2 = (unsigned)(v7 >> 16);
            unsigned e3 = (unsigned)v8;
            unsigned e4 = (unsigned)((v8 >> 32) & 0xFFFF) | ((unsigned)(v9 & 0xFFFF) << 16);
            unsigned e5 = (unsigned)(v9 >> 16);
            unsigned e6 = (unsigned)v10;
            unsigned e7 = (unsigned)((v10 >> 32) & 0xFFFF) | ((unsigned)(v11 & 0xFFFF) << 16);
            *(uint4*)&hlds[ldsB]     = make_uint4(e0, e1, e2, e3);
            *(uint4*)&hlds[ldsB + 8] = make_uint4(e4, e5, e6, e7);
        }
        __syncthreads();

        // ---- GEMM: D[64x16] = W^T (hi+lo) x H ----
        floatx4 acc = {0.f, 0.f, 0.f, 0.f};
        const unsigned short* brow = hlds + c * LROW + q * 8;
        #pragma unroll
        for (int kt = 0; kt < 16; ++kt) {
            short8 bfrag = *(const short8*)(brow + kt * 32);
            acc = __builtin_amdgcn_mfma_f32_16x16x32_bf16(aHi[kt], bfrag, acc, 0, 0, 0);
            acc = __builtin_amdgcn_mfma_f32_16x16x32_bf16(aLo[kt], bfrag, acc, 0, 0, 0);
        }

        // ---- in-lane epilogue ----
        float xv  = xrow[t];
        float aIv = acc[0] + fmaf(xv, w0I, biasI);
        float aFv = acc[1] + fmaf(xv, w0F, biasF);
        float aCv = acc[2] + fmaf(xv, w0C, biasC);
        float aOv = acc[3] + fmaf(xv, w0O, biasO);
        float I  = fast_sigmoid(aIv);
        float F  = fast_sigmoid(aFv);
        float Ch = fast_tanh(aCv);
        Cst = fmaf(F, Cst, I * Ch);
        float Hn = aOv * fast_tanh(Cst);      // reference: O has NO sigmoid

        if (t < SEQ - 1) {
            hout[c * 16 + w * 4 + q] = f2bf(Hn);
            __syncthreads();                  // hout complete; hlds reads done
            if (tid < 96) {                   // assemble + fire this block's 96 units
                unsigned long long val =
                      (unsigned long long)hout[pb16]
                    | ((unsigned long long)hout[pb16 + 1] << 16)
                    | ((unsigned long long)hout[pb16 + 2] << 32)
                    | ((unsigned long long)(t + 1) << 48);
                unsigned long long* uptr = ub + ((t + 1) & 1) * UNITS_PER_SLOT
                                              + g * UNITS_PER_GROUP + punit;
                asm volatile(
                    "global_store_dwordx2 %0, %1, off sc0 sc1\n\t"
                    "s_waitcnt vmcnt(0)"      // data-reg hazard; off critical path (see notes)
                    :: "v"(uptr), "v"(val) : "memory");
            }
        } else {
            int o = bD * HID + colD;
            out[o] = Hn; out[65536 + o] = Hn; out[131072 + o] = Cst;
        }
    }
}

extern "C" void kernel_launch(void* const* d_in, const int* in_sizes, int n_in,
                              void* d_out, int out_size, void* d_ws, size_t ws_size,
                              hipStream_t stream) {
    const float* x  = (const float*)d_in[0];
    const float* H0 = (const float*)d_in[1];
    const float* C0 = (const float*)d_in[2];
    const float* Wi = (const float*)d_in[3];
    const float* bi = (const float*)d_in[4];
    const float* Wf = (const float*)d_in[5];
    const float* bf = (const float*)d_in[6];
    const float* Wc = (const float*)d_in[7];
    const float* bc = (const float*)d_in[8];
    const float* Wo = (const float*)d_in[9];
    const float* bo = (const float*)d_in[10];
    float* out = (float*)d_out;
    unsigned long long* ub = (unsigned long long*)d_ws;   // 2 slots x 192 KB tagged units

    hipLaunchKernelGGL(lstm_init, dim3(UNITS_PER_SLOT / 256), dim3(256), 0, stream,
                       H0, ub);
    hipLaunchKernelGGL(lstm_main, dim3(NGROUP * BPG), dim3(256), 0, stream,
                       x, C0, Wi, bi, Wf, bf, Wc, bc, Wo, bo, out, ub);
}

// Round 9
// 1888.457 us; speedup vs baseline: 2.0381x; 2.0381x over previous
//
#include <hip/hip_runtime.h>
#include <math.h>

#define SEQ 512
#define HID 512
#define NGROUP 8              // batch groups of 16; group g = bid & 7
#define GB 16                 // batches per group (MFMA N)
#define BPG 8                 // blocks per group; each owns 64 cols
#define CPB 64                // cols per block
#define SLOTH 65536           // halves per H slot: [g][b16][k512] fp16 (128 KB)
#define GSLOT 8192            // halves per group per slot (16 KB)
#define LROW 520              // LDS row stride in halves (512 + 8 pad)
// ws layout: 2 fp16 H slots (256 KB) | flags: 8 groups * 128 ints (one per 64B sector)

typedef _Float16 __attribute__((ext_vector_type(8))) half8;   // MFMA A/B frag (4 VGPR)
typedef float __attribute__((ext_vector_type(4))) floatx4;    // MFMA C/D

__device__ __forceinline__ float fast_sigmoid(float x) {
    return 1.0f / (1.0f + __expf(-x));
}
__device__ __forceinline__ float fast_tanh(float x) {
    float e = __expf(-2.0f * fabsf(x));
    float t = (1.0f - e) / (1.0f + e);
    return x < 0.0f ? -t : t;
}

__global__ void lstm_init(const float* __restrict__ H0, _Float16* __restrict__ hb) {
    int idx = blockIdx.x * blockDim.x + threadIdx.x;
    if (idx < SLOTH) {
        int k = idx & 511, b = (idx >> 9) & 15, g = idx >> 13;
        hb[idx] = (_Float16)H0[(g * GB + b) * HID + k];   // slot0 = H(t=0)
    } else if (idx < SLOTH + NGROUP * 128) {
        ((int*)(hb + 2 * SLOTH))[idx - SLOTH] = 0;        // flags = 0
    }
}

__global__ __launch_bounds__(256, 1)
void lstm_main(const float* __restrict__ x,
               const float* __restrict__ C0,
               const float* __restrict__ Wi, const float* __restrict__ bi,
               const float* __restrict__ Wf, const float* __restrict__ bf_,
               const float* __restrict__ Wc, const float* __restrict__ bc,
               const float* __restrict__ Wo, const float* __restrict__ bo,
               float* __restrict__ out, _Float16* __restrict__ hb) {
    int* flags = (int*)(hb + 2 * SLOTH);

    const int bid  = blockIdx.x;
    const int g    = bid & 7;           // group (bid%8 round-robin over XCDs)
    const int cb   = bid >> 3;          // 0..7: 64-col slice
    const int tid  = threadIdx.x;
    const int w    = tid >> 6;          // wave 0..3 (owns cols cb*64 + w*16 + [0,16))
    const int lane = tid & 63;
    const int q    = lane >> 4;         // quad
    const int c    = lane & 15;

    // MFMA roles (verified): A[m=lane&15][k=q*8+j], B[k=q*8+j][n=lane&15],
    // D[m=q*4+r][n=lane&15]; within a 16-m tile: m = local_col*4 + gate.
    const int gate    = c & 3;
    const int colbase = cb * CPB + w * 16;
    const int bD      = g * GB + c;     // this lane's batch (epilogue)

    // ---- step-invariant A-fragments: 4 m-tiles x 16 K-tiles, fp16, in registers ----
    const float* Wg = (gate == 0) ? Wi : (gate == 1) ? Wf : (gate == 2) ? Wc : Wo;
    half8 aW[4][16];
    #pragma unroll
    for (int mt = 0; mt < 4; ++mt) {
        const int colA = colbase + mt * 4 + (c >> 2);
        #pragma unroll
        for (int kt = 0; kt < 16; ++kt) {
            #pragma unroll
            for (int j = 0; j < 8; ++j) {
                int k = kt * 32 + q * 8 + j;
                aW[mt][kt][j] = (_Float16)Wg[(k + 1) * HID + colA]; // rows 1..512 = H wts
            }
        }
    }

    // epilogue constants + C state for this lane's 4 outputs (col = colbase+mt*4+q)
    float biasI[4], biasF[4], biasC[4], biasO[4];
    float w0I[4], w0F[4], w0C[4], w0O[4], Cst[4];
    #pragma unroll
    for (int mt = 0; mt < 4; ++mt) {
        int col = colbase + mt * 4 + q;
        biasI[mt] = bi[col];  biasF[mt] = bf_[col];
        biasC[mt] = bc[col];  biasO[mt] = bo[col];
        w0I[mt] = Wi[col]; w0F[mt] = Wf[col]; w0C[mt] = Wc[col]; w0O[mt] = Wo[col];
        Cst[mt] = C0[bD * HID + col];
    }
    const float* xrow = x + bD * SEQ;

    __shared__ _Float16 hlds[16 * LROW];   // staged H tile [b][k] fp16 (~16.6 KB)
    __shared__ _Float16 hout[16][64];      // this block's step output [b][k_local] (2 KB)

    int* myflag = flags + g * 128 + cb * 16;

    for (int t = 0; t < SEQ; ++t) {
        float xv = xrow[t];                // no dependency on H -- prefetch early

        // ---- wait for this group's 8 producer flags (tiny 4-B polls) ----
        if (tid < BPG) {
            const int* fp = flags + g * 128 + tid * 16;
            while (__hip_atomic_load(fp, __ATOMIC_RELAXED, __HIP_MEMORY_SCOPE_AGENT) < t)
                __builtin_amdgcn_s_sleep(1);
        }
        __syncthreads();

        // ---- stage 16 KB H_t tile once: 64 B/thread coherent burst ----
        {
            const _Float16* gsrc = hb + (t & 1) * SLOTH + g * GSLOT + tid * 32;
            float4 v0, v1, v2, v3;         // float4 outputs: proven asm-safe (R5/R6)
            asm volatile(
                "global_load_dwordx4 %0, %4, off sc0 sc1\n\t"
                "global_load_dwordx4 %1, %4, off offset:16 sc0 sc1\n\t"
                "global_load_dwordx4 %2, %4, off offset:32 sc0 sc1\n\t"
                "global_load_dwordx4 %3, %4, off offset:48 sc0 sc1\n\t"
                "s_waitcnt vmcnt(0)"
                : "=&v"(v0), "=&v"(v1), "=&v"(v2), "=&v"(v3)
                : "v"(gsrc) : "memory");
            int b = tid >> 4, ch = tid & 15;           // 32 halves of batch b, chunk ch
            _Float16* dst = hlds + b * LROW + ch * 32;
            *(float4*)(dst + 0)  = v0;
            *(float4*)(dst + 8)  = v1;
            *(float4*)(dst + 16) = v2;
            *(float4*)(dst + 24) = v3;
        }
        __syncthreads();

        // ---- GEMM: D[64m x 16n] per wave = 4 m-tiles x 16 K-tiles, single fp16 pass ----
        floatx4 acc[4] = {{0.f,0.f,0.f,0.f}, {0.f,0.f,0.f,0.f},
                          {0.f,0.f,0.f,0.f}, {0.f,0.f,0.f,0.f}};
        const _Float16* brow = hlds + c * LROW + q * 8;
        #pragma unroll
        for (int kt = 0; kt < 16; ++kt) {
            half8 bfrag = *(const half8*)(brow + kt * 32);
            #pragma unroll
            for (int mt = 0; mt < 4; ++mt)
                acc[mt] = __builtin_amdgcn_mfma_f32_16x16x32_f16(aW[mt][kt], bfrag,
                                                                 acc[mt], 0, 0, 0);
        }

        // ---- in-lane epilogue: 4 (col, b) outputs per thread ----
        float Hn[4];
        #pragma unroll
        for (int mt = 0; mt < 4; ++mt) {
            float aIv = acc[mt][0] + fmaf(xv, w0I[mt], biasI[mt]);
            float aFv = acc[mt][1] + fmaf(xv, w0F[mt], biasF[mt]);
            float aCv = acc[mt][2] + fmaf(xv, w0C[mt], biasC[mt]);
            float aOv = acc[mt][3] + fmaf(xv, w0O[mt], biasO[mt]);
            float I  = fast_sigmoid(aIv);
            float F  = fast_sigmoid(aFv);
            float Ch = fast_tanh(aCv);
            Cst[mt] = fmaf(F, Cst[mt], I * Ch);
            Hn[mt]  = aOv * fast_tanh(Cst[mt]);    // reference: O has NO sigmoid
        }

        if (t < SEQ - 1) {
            #pragma unroll
            for (int mt = 0; mt < 4; ++mt)
                hout[c][w * 16 + mt * 4 + q] = (_Float16)Hn[mt];
            __syncthreads();               // hout complete; hlds reads long done
            if (tid < 128) {               // block's 2 KB: 16 b-rows x 128 B, 16 B/thread
                int b = tid >> 3, ch = tid & 7;
                // u64 inputs: the only asm input type proven to compile (R6)
                unsigned long long s0 = *(const unsigned long long*)&hout[b][ch * 8];
                unsigned long long s1 = *(const unsigned long long*)&hout[b][ch * 8 + 4];
                _Float16* dst = hb + ((t + 1) & 1) * SLOTH + g * GSLOT
                                + b * HID + cb * CPB + ch * 8;
                asm volatile(
                    "global_store_dwordx2 %0, %1, off sc0 sc1\n\t"
                    "global_store_dwordx2 %0, %2, off offset:8 sc0 sc1\n\t"
                    "s_waitcnt vmcnt(0)"   // own stores at coherent point before barrier
                    :: "v"(dst), "v"(s0), "v"(s1) : "memory");
            }
            __syncthreads();               // all producers' stores ack'd
            if (tid == 0)
                __hip_atomic_store(myflag, t + 1, __ATOMIC_RELAXED, __HIP_MEMORY_SCOPE_AGENT);
        } else {
            #pragma unroll
            for (int mt = 0; mt < 4; ++mt) {
                int o = bD * HID + colbase + mt * 4 + q;
                out[o] = Hn[mt]; out[65536 + o] = Hn[mt]; out[131072 + o] = Cst[mt];
            }
        }
    }
}

extern "C" void kernel_launch(void* const* d_in, const int* in_sizes, int n_in,
                              void* d_out, int out_size, void* d_ws, size_t ws_size,
                              hipStream_t stream) {
    const float* x  = (const float*)d_in[0];
    const float* H0 = (const float*)d_in[1];
    const float* C0 = (const float*)d_in[2];
    const float* Wi = (const float*)d_in[3];
    const float* bi = (const float*)d_in[4];
    const float* Wf = (const float*)d_in[5];
    const float* bf = (const float*)d_in[6];
    const float* Wc = (const float*)d_in[7];
    const float* bc = (const float*)d_in[8];
    const float* Wo = (const float*)d_in[9];
    const float* bo = (const float*)d_in[10];
    float* out = (float*)d_out;
    _Float16* hb = (_Float16*)d_ws;   // 256 KB H slots + 4 KB flags

    const int init_elems = SLOTH + NGROUP * 128;
    hipLaunchKernelGGL(lstm_init, dim3((init_elems + 255) / 256), dim3(256), 0, stream,
                       H0, hb);
    hipLaunchKernelGGL(lstm_main, dim3(NGROUP * BPG), dim3(256), 0, stream,
                       x, C0, Wi, bi, Wf, bf, Wc, bc, Wo, bo, out, hb);
}

// Round 12
// 1695.419 us; speedup vs baseline: 2.2701x; 1.1139x over previous
//
#include <hip/hip_runtime.h>
#include <math.h>

#define SEQ 512
#define HID 512
#define NGROUP 8              // batch groups of 16; group g = bid & 7
#define GB 16                 // batches per group (MFMA N)
#define BPG 32                // blocks per group; each owns 16 cols
#define CPB 16                // cols per block
#define SLOTH 65536           // halves per H slot: [g][b16][k512] fp16 (128 KB)
#define GSLOT 8192            // halves per group per slot (16 KB)
#define LROW 520              // LDS row stride in halves (512 + 8 pad)
// ws: 2 fp16 H slots (256 KB) | flags int[8][64] (32 used per group)
// Handshake = R6-proven semantics ONLY: payload stores sc0 sc1 (coherent point),
// per-wave vmcnt(0) ack, __syncthreads, THEN device-scope flag store. R11's
// sc0-local variant produced stale-H accumulation in C -- do not retry.

typedef _Float16 __attribute__((ext_vector_type(8))) half8;   // MFMA A/B frag
typedef float __attribute__((ext_vector_type(4))) floatx4;    // MFMA C/D

__device__ __forceinline__ float fast_sigmoid(float x) {
    return 1.0f / (1.0f + __expf(-x));
}
__device__ __forceinline__ float fast_tanh(float x) {
    float e = __expf(-2.0f * fabsf(x));
    float t = (1.0f - e) / (1.0f + e);
    return x < 0.0f ? -t : t;
}

__global__ void lstm_init(const float* __restrict__ H0, _Float16* __restrict__ hb) {
    int idx = blockIdx.x * blockDim.x + threadIdx.x;
    if (idx < SLOTH) {
        int k = idx & 511, b = (idx >> 9) & 15, g = idx >> 13;
        hb[idx] = (_Float16)H0[(g * GB + b) * HID + k];   // slot0 = H(t=0)
    } else if (idx < SLOTH + NGROUP * 64) {
        ((int*)(hb + 2 * SLOTH))[idx - SLOTH] = 0;        // flags = 0
    }
}

__global__ __launch_bounds__(256, 1)
void lstm_main(const float* __restrict__ x,
               const float* __restrict__ C0,
               const float* __restrict__ Wi, const float* __restrict__ bi,
               const float* __restrict__ Wf, const float* __restrict__ bf_,
               const float* __restrict__ Wc, const float* __restrict__ bc,
               const float* __restrict__ Wo, const float* __restrict__ bo,
               float* __restrict__ out, _Float16* __restrict__ hb) {
    int* flags = (int*)(hb + 2 * SLOTH);

    const int bid  = blockIdx.x;
    const int g    = bid & 7;           // group (bid%8 round-robin over XCDs)
    const int cb   = bid >> 3;          // 0..31: which 16-col slice this block owns
    const int tid  = threadIdx.x;
    const int w    = tid >> 6;          // wave 0..3 (cols cb*16 + w*4 + [0,4))
    const int lane = tid & 63;
    const int q    = lane >> 4;         // quad
    const int c    = lane & 15;

    // MFMA roles (verified): A[m=lane&15][k=q*8+j], B[k=q*8+j][n=lane&15],
    // D[m=q*4+r][n=lane&15]; m = local_col*4 + gate.
    const int gate = c & 3;
    const int colA = cb * CPB + w * 4 + (c >> 2);
    const int colD = cb * CPB + w * 4 + q;    // this lane's output column
    const int bD   = g * GB + c;              // this lane's batch

    // ---- step-invariant A-fragments: 16 K-tiles fp16 = 64 VGPRs (no spill) ----
    const float* Wg = (gate == 0) ? Wi : (gate == 1) ? Wf : (gate == 2) ? Wc : Wo;
    half8 aW[16];
    #pragma unroll
    for (int kt = 0; kt < 16; ++kt) {
        #pragma unroll
        for (int j = 0; j < 8; ++j) {
            int k = kt * 32 + q * 8 + j;
            aW[kt][j] = (_Float16)Wg[(k + 1) * HID + colA];   // rows 1..512 = H wts
        }
    }

    const float biasI = bi[colD], biasF = bf_[colD], biasC = bc[colD], biasO = bo[colD];
    const float w0I = Wi[colD], w0F = Wf[colD], w0C = Wc[colD], w0O = Wo[colD];
    float Cst = C0[bD * HID + colD];
    const float* xrow = x + bD * SEQ;

    __shared__ _Float16 hlds[16 * LROW];   // staged H tile [b][k] fp16 (16.6 KB)

    int* myflag = flags + g * 64 + cb;

    for (int t = 0; t < SEQ; ++t) {
        float xv = xrow[t];                // no H dependency -- prefetch early

        // ---- wait for this group's 32 producer flags (proven R6 poll) ----
        if (tid < BPG) {
            const int* fp = flags + g * 64 + tid;
            while (__hip_atomic_load(fp, __ATOMIC_RELAXED, __HIP_MEMORY_SCOPE_AGENT) < t)
                __builtin_amdgcn_s_sleep(1);
        }
        __syncthreads();

        // ---- stage 16 KB H_t tile once: 64 B/thread coherent burst (R6 exact) ----
        {
            const _Float16* gsrc = hb + (t & 1) * SLOTH + g * GSLOT + tid * 32;
            float4 v0, v1, v2, v3;
            asm volatile(
                "global_load_dwordx4 %0, %4, off sc0 sc1\n\t"
                "global_load_dwordx4 %1, %4, off offset:16 sc0 sc1\n\t"
                "global_load_dwordx4 %2, %4, off offset:32 sc0 sc1\n\t"
                "global_load_dwordx4 %3, %4, off offset:48 sc0 sc1\n\t"
                "s_waitcnt vmcnt(0)"
                : "=&v"(v0), "=&v"(v1), "=&v"(v2), "=&v"(v3)
                : "v"(gsrc) : "memory");
            int b = tid >> 4, ch = tid & 15;
            _Float16* dst = hlds + b * LROW + ch * 32;
            *(float4*)(dst + 0)  = v0;
            *(float4*)(dst + 8)  = v1;
            *(float4*)(dst + 16) = v2;
            *(float4*)(dst + 24) = v3;
        }
        __syncthreads();

        // ---- GEMM: D[16m x 16n] per wave, 16 K-tiles, single fp16 pass ----
        floatx4 acc = {0.f, 0.f, 0.f, 0.f};
        const _Float16* brow = hlds + c * LROW + q * 8;
        #pragma unroll
        for (int kt = 0; kt < 16; ++kt) {
            half8 bfrag = *(const half8*)(brow + kt * 32);
            acc = __builtin_amdgcn_mfma_f32_16x16x32_f16(aW[kt], bfrag, acc, 0, 0, 0);
        }

        // ---- in-lane epilogue: one (colD, bD) output per thread ----
        float aIv = acc[0] + fmaf(xv, w0I, biasI);
        float aFv = acc[1] + fmaf(xv, w0F, biasF);
        float aCv = acc[2] + fmaf(xv, w0C, biasC);
        float aOv = acc[3] + fmaf(xv, w0O, biasO);
        float I  = fast_sigmoid(aIv);
        float F  = fast_sigmoid(aFv);
        float Ch = fast_tanh(aCv);
        Cst = fmaf(F, Cst, I * Ch);
        float Hn = aOv * fast_tanh(Cst);      // reference: O has NO sigmoid

        if (t < SEQ - 1) {
            // shuffle-pack 4 cols (q=0..3) of batch c into 8 B; q==0 lanes store.
            int hv = (int)__builtin_bit_cast(unsigned short, (_Float16)Hn);
            int h1 = __shfl(hv, c + 16);
            int h2 = __shfl(hv, c + 32);
            int h3 = __shfl(hv, c + 48);
            if (q == 0) {
                unsigned long long val =
                      (unsigned long long)(unsigned short)hv
                    | ((unsigned long long)(unsigned short)h1 << 16)
                    | ((unsigned long long)(unsigned short)h2 << 32)
                    | ((unsigned long long)(unsigned short)h3 << 48);
                _Float16* dst = hb + ((t + 1) & 1) * SLOTH + g * GSLOT
                                + c * HID + cb * CPB + w * 4;
                asm volatile(
                    "global_store_dwordx2 %0, %1, off sc0 sc1\n\t"
                    "s_waitcnt vmcnt(0)"      // payload at coherent point before flag
                    :: "v"(dst), "v"(val) : "memory");
            }
            __syncthreads();                  // all waves' stores ack'd
            if (tid == 0)
                __hip_atomic_store(myflag, t + 1, __ATOMIC_RELAXED, __HIP_MEMORY_SCOPE_AGENT);
        } else {
            int o = bD * HID + colD;
            out[o] = Hn; out[65536 + o] = Hn; out[131072 + o] = Cst;
        }
    }
}

extern "C" void kernel_launch(void* const* d_in, const int* in_sizes, int n_in,
                              void* d_out, int out_size, void* d_ws, size_t ws_size,
                              hipStream_t stream) {
    const float* x  = (const float*)d_in[0];
    const float* H0 = (const float*)d_in[1];
    const float* C0 = (const float*)d_in[2];
    const float* Wi = (const float*)d_in[3];
    const float* bi = (const float*)d_in[4];
    const float* Wf = (const float*)d_in[5];
    const float* bf = (const float*)d_in[6];
    const float* Wc = (const float*)d_in[7];
    const float* bc = (const float*)d_in[8];
    const float* Wo = (const float*)d_in[9];
    const float* bo = (const float*)d_in[10];
    float* out = (float*)d_out;
    _Float16* hb = (_Float16*)d_ws;   // 256 KB H slots + flags

    const int init_elems = SLOTH + NGROUP * 64;
    hipLaunchKernelGGL(lstm_init, dim3((init_elems + 255) / 256), dim3(256), 0, stream,
                       H0, hb);
    hipLaunchKernelGGL(lstm_main, dim3(NGROUP * BPG), dim3(256), 0, stream,
                       x, C0, Wi, bi, Wf, bf, Wc, bc, Wo, bo, out, hb);
}